// Round 4
// baseline (329.098 us; speedup 1.0000x reference)
//
#include <hip/hip_runtime.h>
#include <stdint.h>

#define IN_F   8192
#define OUT_F  8192
#define MB     64
#define RANK   16
#define KSPLIT 4
#define BK     256
#define NTILE  128
#define XS_STRIDE 264   // ushorts per LDS row: 256 + 8 pad (132 dwords, 16B-aligned)

typedef _Float16 f16x8 __attribute__((ext_vector_type(8)));
typedef float    f32x4 __attribute__((ext_vector_type(4)));
typedef unsigned u32x4 __attribute__((ext_vector_type(4)));

// pack two f32 -> two f16 (RTZ), return as 4-byte unsigned
__device__ __forceinline__ unsigned pk2h(float a, float b) {
    return __builtin_bit_cast(unsigned, __builtin_amdgcn_cvt_pkrtz(a, b));
}

// nvfp4 e2m1 decode: nibble LUT of 2*|value| packed as nibbles of 0xC8643210,
// sign from bit 3; the *0.5 is folded into the (pre-halved) block scale.
__device__ __forceinline__ float decode_fp4(unsigned nib, float schalf) {
    unsigned c = nib & 0xFu;
    int hv = (int)((0xC8643210u >> ((c & 7u) * 4u)) & 0xFu);
    int iv = (c & 8u) ? -hv : hv;
    return (float)iv * schalf;
}

// one packed byte (2 codes) -> 2 f16 in a dword (low = even k)
__device__ __forceinline__ unsigned dec_byte(unsigned bv, float schalf) {
    return pk2h(decode_fp4(bv, schalf), decode_fp4(bv >> 4, schalf));
}

// Detect upload format of packed_weight: int32-per-byte (harness "integer->int*")
// vs raw uint8. First 64 words all <=255 <=> int32 (misdetect p ~ 2^-24*64).
__global__ void detect_kernel(const unsigned* __restrict__ Wp, int* __restrict__ flag) {
    unsigned v = Wp[threadIdx.x & 63];
    unsigned long long m = __ballot(v > 255u);
    if (threadIdx.x == 0) *flag = (m == 0ull) ? 1 : 0;
}

// Kernel 1 (one block per m row):
//   xh[m] = fp16(x[m]);  t = x[m].A^T;  out[m][:] = t.B^T  (main adds base on top)
__global__ __launch_bounds__(256) void prep_kernel(
    const float* __restrict__ x, const float* __restrict__ lora_A,
    const float* __restrict__ lora_B,
    uint2* __restrict__ xh, float* __restrict__ out)
{
    const int m = blockIdx.x;
    const int tid = threadIdx.x;
    float acc[RANK];
#pragma unroll
    for (int r = 0; r < RANK; ++r) acc[r] = 0.f;

    const float4* x4 = (const float4*)(x + (size_t)m * IN_F);
    const float4* A4 = (const float4*)lora_A;
    for (int j = tid; j < IN_F / 4; j += 256) {
        float4 xv = x4[j];
        uint2 u;
        u.x = pk2h(xv.x, xv.y);
        u.y = pk2h(xv.z, xv.w);
        xh[(size_t)m * (IN_F / 4) + j] = u;
#pragma unroll
        for (int r = 0; r < RANK; ++r) {
            float4 av = A4[(size_t)r * (IN_F / 4) + j];
            acc[r] += xv.x * av.x + xv.y * av.y + xv.z * av.z + xv.w * av.w;
        }
    }
#pragma unroll
    for (int r = 0; r < RANK; ++r)
#pragma unroll
        for (int off = 32; off > 0; off >>= 1)
            acc[r] += __shfl_down(acc[r], off);

    __shared__ float red[4][RANK];
    __shared__ __align__(16) float tsh[RANK];
    int lane = tid & 63, wid = tid >> 6;
    if (lane == 0) {
#pragma unroll
        for (int r = 0; r < RANK; ++r) red[wid][r] = acc[r];
    }
    __syncthreads();
    if (tid < RANK)
        tsh[tid] = red[0][tid] + red[1][tid] + red[2][tid] + red[3][tid];
    __syncthreads();

    float4 ta = *(const float4*)&tsh[0];
    float4 tb = *(const float4*)&tsh[4];
    float4 tc = *(const float4*)&tsh[8];
    float4 td = *(const float4*)&tsh[12];
    float* orow = out + (size_t)m * OUT_F;
#pragma unroll 4
    for (int j = 0; j < OUT_F / 256; ++j) {
        int n = j * 256 + tid;
        const float4* B4 = (const float4*)(lora_B + (size_t)n * RANK);
        float4 b0 = B4[0], b1 = B4[1], b2 = B4[2], b3 = B4[3];
        orow[n] = ta.x * b0.x + ta.y * b0.y + ta.z * b0.z + ta.w * b0.w
                + tb.x * b1.x + tb.y * b1.y + tb.z * b1.z + tb.w * b1.w
                + tc.x * b2.x + tc.y * b2.y + tc.z * b2.z + tc.w * b2.w
                + td.x * b3.x + td.y * b3.y + td.z * b3.z + td.w * b3.w;
    }
}

// Kernel 2: fused dequant + GEMM, K-split; MFMA partials atomicAdd'ed onto out.
// FMT=1: packed_weight is int32 (one byte value per element, harness int upload)
// FMT=0: packed_weight is raw uint8. Wrong-format dispatch early-exits on flag.
template<int FMT>
__global__ __launch_bounds__(256) void main_kernel(
    const void*  __restrict__ Wpv,
    const float* __restrict__ scales,
    const uint4* __restrict__ xh,
    const int*   __restrict__ flag,
    float*       __restrict__ out)
{
    if (*flag != FMT) return;

    __shared__ __align__(16) ushort xs[64 * XS_STRIDE];

    const int ks  = blockIdx.x;
    const int nb  = blockIdx.y;
    const int tid = threadIdx.x;
    const int lane = tid & 63, w = tid >> 6;
    const int l15 = lane & 15, quad = lane >> 4;

    const int kbase = ks * (IN_F / KSPLIT);   // 2048
    const int n0 = nb * NTILE + w * 32;       // wave n base (2 tiles of 16)

    f32x4 acc[4][2];
#pragma unroll
    for (int mt = 0; mt < 4; ++mt)
#pragma unroll
        for (int nt = 0; nt < 2; ++nt)
            acc[mt][nt] = (f32x4){0.f, 0.f, 0.f, 0.f};

    // per-lane W row pointers (row = n0 + l15 [+16 for nt=1])
    const int4*    wi0 = (const int4*)Wpv + (size_t)(n0 + l15) * (IN_F / 2 / 4);
    const int4*    wi1 = wi0 + (size_t)16 * (IN_F / 2 / 4);
    const uint8_t* wb0 = (const uint8_t*)Wpv + (size_t)(n0 + l15) * (IN_F / 2);
    const uint8_t* wb1 = wb0 + (size_t)16 * (IN_F / 2);
    const float*   sp0 = scales + (size_t)(n0 + l15) * (IN_F / 16);
    const float*   sp1 = sp0 + (size_t)16 * (IN_F / 16);

    for (int stage = 0; stage < (IN_F / KSPLIT) / BK; ++stage) {
        const int k0 = kbase + stage * BK;
        __syncthreads();
        // stage 64 x 256 halves of xh into LDS: 2048 16B-chunks, 8 per thread
#pragma unroll
        for (int j = 0; j < 8; ++j) {
            int chunk = tid + j * 256;
            int row = chunk >> 5, c = chunk & 31;
            uint4 v = xh[(size_t)row * (IN_F / 8) + (k0 >> 3) + c];
            *(uint4*)&xs[row * XS_STRIDE + c * 8] = v;
        }
        __syncthreads();

#pragma unroll
        for (int s = 0; s < BK / 32; ++s) {   // 8 k-steps of 32
            f16x8 afr[4];
#pragma unroll
            for (int mt = 0; mt < 4; ++mt) {
                int row = mt * 16 + l15;
                afr[mt] = *(const f16x8*)&xs[row * XS_STRIDE + s * 32 + quad * 8];
            }
            const int kk = k0 + s * 32 + quad * 8;   // lane's global k (8 codes)
#pragma unroll
            for (int nt = 0; nt < 2; ++nt) {
                const float* sp = nt ? sp1 : sp0;
                float schalf = 0.5f * sp[kk >> 4];   // 8 codes stay in one 16-group
                unsigned by0, by1, by2, by3;         // 4 packed bytes = 8 codes
                if (FMT == 1) {
                    const int4* wi = nt ? wi1 : wi0;
                    int4 v = wi[kk >> 3];            // 4 int32, one byte each
                    by0 = (unsigned)v.x; by1 = (unsigned)v.y;
                    by2 = (unsigned)v.z; by3 = (unsigned)v.w;
                } else {
                    const uint8_t* wb = nt ? wb1 : wb0;
                    unsigned w32 = *(const unsigned*)(wb + (kk >> 1));
                    by0 = w32 & 0xFFu; by1 = (w32 >> 8) & 0xFFu;
                    by2 = (w32 >> 16) & 0xFFu; by3 = w32 >> 24;
                }
                u32x4 bu;
                bu[0] = dec_byte(by0, schalf);
                bu[1] = dec_byte(by1, schalf);
                bu[2] = dec_byte(by2, schalf);
                bu[3] = dec_byte(by3, schalf);
                f16x8 b = __builtin_bit_cast(f16x8, bu);
#pragma unroll
                for (int mt = 0; mt < 4; ++mt)
                    acc[mt][nt] = __builtin_amdgcn_mfma_f32_16x16x32_f16(
                        afr[mt], b, acc[mt][nt], 0, 0, 0);
            }
        }
    }

    // epilogue: C/D layout col(n)=lane&15, row(m)=quad*4+reg; accumulate onto out
#pragma unroll
    for (int mt = 0; mt < 4; ++mt)
#pragma unroll
        for (int nt = 0; nt < 2; ++nt)
#pragma unroll
            for (int r = 0; r < 4; ++r) {
                int m = mt * 16 + quad * 4 + r;
                int n = n0 + nt * 16 + l15;
                atomicAdd(&out[(size_t)m * OUT_F + n], acc[mt][nt][r]);
            }
}

extern "C" void kernel_launch(void* const* d_in, const int* in_sizes, int n_in,
                              void* d_out, int out_size, void* d_ws, size_t ws_size,
                              hipStream_t stream)
{
    (void)in_sizes; (void)n_in; (void)out_size; (void)ws_size;
    const float* x      = (const float*)d_in[0];
    const void*  Wp     = (const void*)d_in[1];
    const float* scales = (const float*)d_in[2];
    const float* lora_A = (const float*)d_in[3];
    const float* lora_B = (const float*)d_in[4];
    float* out = (float*)d_out;

    char* ws = (char*)d_ws;
    int*   flag = (int*)ws;                 // 4 B
    uint2* xh   = (uint2*)(ws + 4096);      // 1 MiB fp16 x

    detect_kernel<<<1, 64, 0, stream>>>((const unsigned*)Wp, flag);
    prep_kernel<<<64, 256, 0, stream>>>(x, lora_A, lora_B, xh, out);
    main_kernel<1><<<dim3(KSPLIT, OUT_F / NTILE), 256, 0, stream>>>(
        Wp, scales, (const uint4*)xh, flag, out);
    main_kernel<0><<<dim3(KSPLIT, OUT_F / NTILE), 256, 0, stream>>>(
        Wp, scales, (const uint4*)xh, flag, out);
}

// Round 5
// 276.944 us; speedup vs baseline: 1.1883x; 1.1883x over previous
//
#include <hip/hip_runtime.h>
#include <stdint.h>

#define IN_F   8192
#define OUT_F  8192
#define MB     64
#define RANK   16
#define KSPLIT 16
#define NTILE  128

typedef _Float16 f16x8 __attribute__((ext_vector_type(8)));
typedef float    f32x4 __attribute__((ext_vector_type(4)));
typedef unsigned u32x4 __attribute__((ext_vector_type(4)));

// pack two f32 -> two f16 (RTZ), return as 4-byte unsigned
__device__ __forceinline__ unsigned pk2h(float a, float b) {
    return __builtin_bit_cast(unsigned, __builtin_amdgcn_cvt_pkrtz(a, b));
}

// nvfp4 e2m1 decode: nibble LUT of 2*|value| packed as nibbles of 0xC8643210,
// sign from bit 3; the *0.5 is folded into the (pre-halved) block scale.
__device__ __forceinline__ float decode_fp4(unsigned nib, float schalf) {
    unsigned c = nib & 0xFu;
    int hv = (int)((0xC8643210u >> ((c & 7u) * 4u)) & 0xFu);
    int iv = (c & 8u) ? -hv : hv;
    return (float)iv * schalf;
}

// one packed byte (2 codes) -> 2 f16 in a dword (low = even k)
__device__ __forceinline__ unsigned dec_byte(unsigned bv, float schalf) {
    return pk2h(decode_fp4(bv, schalf), decode_fp4(bv >> 4, schalf));
}

// Detect upload format of packed_weight: int32-per-byte vs raw uint8.
__global__ void detect_kernel(const unsigned* __restrict__ Wp, int* __restrict__ flag) {
    unsigned v = Wp[threadIdx.x & 63];
    unsigned long long m = __ballot(v > 255u);
    if (threadIdx.x == 0) *flag = (m == 0ull) ? 1 : 0;
}

// Kernel 1 (one block per m row):
//   xf = fp16(x) in MFMA-A-fragment layout:
//        frag(kstep,mt,lane=quad*16+l15)[j] = x[mt*16+l15][kstep*32+quad*8+j]
//        stored at 16B index (kstep*4+mt)*64 + lane
//   t = x[m].A^T;  out[m][:] = t.B^T  (main adds base on top)
__global__ __launch_bounds__(256) void prep_kernel(
    const float* __restrict__ x, const float* __restrict__ lora_A,
    const float* __restrict__ lora_B,
    uint2* __restrict__ xf2, float* __restrict__ out)
{
    const int m = blockIdx.x;
    const int tid = threadIdx.x;
    const int mt = m >> 4, l15 = m & 15;
    float acc[RANK];
#pragma unroll
    for (int r = 0; r < RANK; ++r) acc[r] = 0.f;

    const float4* x4 = (const float4*)(x + (size_t)m * IN_F);
    const float4* A4 = (const float4*)lora_A;
    for (int j = tid; j < IN_F / 4; j += 256) {
        float4 xv = x4[j];
        uint2 u;
        u.x = pk2h(xv.x, xv.y);
        u.y = pk2h(xv.z, xv.w);
        // fragment coords for k = 4j..4j+3
        int kstep = j >> 3, quad = (j >> 1) & 3, h = j & 1;
        xf2[(size_t)(((kstep * 4 + mt) * 64 + quad * 16 + l15) * 2 + h)] = u;
#pragma unroll
        for (int r = 0; r < RANK; ++r) {
            float4 av = A4[(size_t)r * (IN_F / 4) + j];
            acc[r] += xv.x * av.x + xv.y * av.y + xv.z * av.z + xv.w * av.w;
        }
    }
#pragma unroll
    for (int r = 0; r < RANK; ++r)
#pragma unroll
        for (int off = 32; off > 0; off >>= 1)
            acc[r] += __shfl_down(acc[r], off);

    __shared__ float red[4][RANK];
    __shared__ __align__(16) float tsh[RANK];
    int lane = tid & 63, wid = tid >> 6;
    if (lane == 0) {
#pragma unroll
        for (int r = 0; r < RANK; ++r) red[wid][r] = acc[r];
    }
    __syncthreads();
    if (tid < RANK)
        tsh[tid] = red[0][tid] + red[1][tid] + red[2][tid] + red[3][tid];
    __syncthreads();

    float4 ta = *(const float4*)&tsh[0];
    float4 tb = *(const float4*)&tsh[4];
    float4 tc = *(const float4*)&tsh[8];
    float4 td = *(const float4*)&tsh[12];
    float* orow = out + (size_t)m * OUT_F;
#pragma unroll 4
    for (int j = 0; j < OUT_F / 256; ++j) {
        int n = j * 256 + tid;
        const float4* B4 = (const float4*)(lora_B + (size_t)n * RANK);
        float4 b0 = B4[0], b1 = B4[1], b2 = B4[2], b3 = B4[3];
        orow[n] = ta.x * b0.x + ta.y * b0.y + ta.z * b0.z + ta.w * b0.w
                + tb.x * b1.x + tb.y * b1.y + tb.z * b1.z + tb.w * b1.w
                + tc.x * b2.x + tc.y * b2.y + tc.z * b2.z + tc.w * b2.w
                + td.x * b3.x + td.y * b3.y + td.z * b3.z + td.w * b3.w;
    }
}

// Kernel 2: fused dequant + GEMM. No LDS, no barriers — A-fragments come
// pre-swizzled from L2-resident xf. grid=(KSPLIT,64), block=256 (4 waves).
// Wave w: 64 M x 32 N, K-range 512. MFMA partials atomicAdd'ed onto out.
template<int FMT>
__global__ __launch_bounds__(256) void main_kernel(
    const void*  __restrict__ Wpv,
    const float* __restrict__ scales,
    const uint4* __restrict__ xf4,   // fragment-layout x, 16B units
    const int*   __restrict__ flag,
    float*       __restrict__ out)
{
    if (*flag != FMT) return;

    const int ks  = blockIdx.x;
    const int nb  = blockIdx.y;
    const int tid = threadIdx.x;
    const int lane = tid & 63, w = tid >> 6;
    const int l15 = lane & 15, quad = lane >> 4;

    const int kbase   = ks * (IN_F / KSPLIT);   // 512
    const int kbase32 = kbase >> 5;
    const int n0 = nb * NTILE + w * 32;

    f32x4 acc[4][2];
#pragma unroll
    for (int mt = 0; mt < 4; ++mt)
#pragma unroll
        for (int nt = 0; nt < 2; ++nt)
            acc[mt][nt] = (f32x4){0.f, 0.f, 0.f, 0.f};

    // per-lane W row pointers (row = n0 + l15 [+16 for nt=1])
    const int4*    wi0 = (const int4*)Wpv + (size_t)(n0 + l15) * (IN_F / 2 / 4);
    const int4*    wi1 = wi0 + (size_t)16 * (IN_F / 2 / 4);
    const uint8_t* wb0 = (const uint8_t*)Wpv + (size_t)(n0 + l15) * (IN_F / 2);
    const uint8_t* wb1 = wb0 + (size_t)16 * (IN_F / 2);
    const float*   sp0 = scales + (size_t)(n0 + l15) * (IN_F / 16);
    const float*   sp1 = sp0 + (size_t)16 * (IN_F / 16);

#pragma unroll 4
    for (int s = 0; s < (IN_F / KSPLIT) / 32; ++s) {   // 16 k-steps of 32
        const int kstep = kbase32 + s;
        // A fragments: one coalesced 16B load per m-tile
        f16x8 afr[4];
#pragma unroll
        for (int mt = 0; mt < 4; ++mt)
            afr[mt] = __builtin_bit_cast(f16x8, xf4[(size_t)(kstep * 4 + mt) * 64 + lane]);

        const int kk = kbase + s * 32 + quad * 8;   // lane's global k (8 codes)
#pragma unroll
        for (int nt = 0; nt < 2; ++nt) {
            const float* sp = nt ? sp1 : sp0;
            float schalf = 0.5f * sp[kk >> 4];
            unsigned by0, by1, by2, by3;            // 4 packed bytes = 8 codes
            if (FMT == 1) {
                const int4* wi = nt ? wi1 : wi0;
                int4 v = wi[kk >> 3];               // 4 int32, one byte each
                by0 = (unsigned)v.x; by1 = (unsigned)v.y;
                by2 = (unsigned)v.z; by3 = (unsigned)v.w;
            } else {
                const uint8_t* wb = nt ? wb1 : wb0;
                unsigned w32 = *(const unsigned*)(wb + (kk >> 1));
                by0 = w32 & 0xFFu; by1 = (w32 >> 8) & 0xFFu;
                by2 = (w32 >> 16) & 0xFFu; by3 = w32 >> 24;
            }
            u32x4 bu;
            bu[0] = dec_byte(by0, schalf);
            bu[1] = dec_byte(by1, schalf);
            bu[2] = dec_byte(by2, schalf);
            bu[3] = dec_byte(by3, schalf);
            f16x8 b = __builtin_bit_cast(f16x8, bu);
#pragma unroll
            for (int mt = 0; mt < 4; ++mt)
                acc[mt][nt] = __builtin_amdgcn_mfma_f32_16x16x32_f16(
                    afr[mt], b, acc[mt][nt], 0, 0, 0);
        }
    }

    // epilogue: C/D layout col(n)=lane&15, row(m)=quad*4+reg; accumulate onto out
#pragma unroll
    for (int mt = 0; mt < 4; ++mt)
#pragma unroll
        for (int nt = 0; nt < 2; ++nt)
#pragma unroll
            for (int r = 0; r < 4; ++r) {
                int m = mt * 16 + quad * 4 + r;
                int n = n0 + nt * 16 + l15;
                atomicAdd(&out[(size_t)m * OUT_F + n], acc[mt][nt][r]);
            }
}

extern "C" void kernel_launch(void* const* d_in, const int* in_sizes, int n_in,
                              void* d_out, int out_size, void* d_ws, size_t ws_size,
                              hipStream_t stream)
{
    (void)in_sizes; (void)n_in; (void)out_size; (void)ws_size;
    const float* x      = (const float*)d_in[0];
    const void*  Wp     = (const void*)d_in[1];
    const float* scales = (const float*)d_in[2];
    const float* lora_A = (const float*)d_in[3];
    const float* lora_B = (const float*)d_in[4];
    float* out = (float*)d_out;

    char* ws = (char*)d_ws;
    int*   flag = (int*)ws;                 // 4 B
    uint2* xf   = (uint2*)(ws + 4096);      // 1 MiB fragment-layout fp16 x

    detect_kernel<<<1, 64, 0, stream>>>((const unsigned*)Wp, flag);
    prep_kernel<<<64, 256, 0, stream>>>(x, lora_A, lora_B, xf, out);
    main_kernel<1><<<dim3(KSPLIT, OUT_F / NTILE), 256, 0, stream>>>(
        Wp, scales, (const uint4*)xf, flag, out);
    main_kernel<0><<<dim3(KSPLIT, OUT_F / NTILE), 256, 0, stream>>>(
        Wp, scales, (const uint4*)xf, flag, out);
}

// Round 6
// 258.424 us; speedup vs baseline: 1.2735x; 1.0717x over previous
//
#include <hip/hip_runtime.h>
#include <stdint.h>

#define IN_F   8192
#define OUT_F  8192
#define MB     64
#define RANK   16

typedef _Float16 f16x8 __attribute__((ext_vector_type(8)));
typedef _Float16 f16x2 __attribute__((ext_vector_type(2)));
typedef float    f32x4 __attribute__((ext_vector_type(4)));

__device__ __forceinline__ unsigned pk2h(float a, float b) {
    return __builtin_bit_cast(unsigned, __builtin_amdgcn_cvt_pkrtz(a, b));
}

// Decode 8 nvfp4 codes (packed dword p, byte i = codes 2i,2i+1) into f16x8
// scaled by s2 (f16x2 of block scale). v_perm LUT: f16 magnitudes of
// {0,.5,1,1.5,2,3,4,6} = hi-bytes {00,38,3C,3E,40,42,44,46}, low byte 0.
// sign: bit3 of nibble -> bit7 of hi-byte via <<4. sel 0x0C = zero byte.
__device__ __forceinline__ f16x8 decode8(unsigned p, unsigned s2) {
    unsigned q  = p >> 4;
    unsigned me = __builtin_amdgcn_perm(0x46444240u, 0x3E3C3800u, p & 0x07070707u);
    unsigned mo = __builtin_amdgcn_perm(0x46444240u, 0x3E3C3800u, q & 0x07070707u);
    unsigned he = ((p & 0x08080808u) << 4) | me;   // hi-bytes, even codes (k+0,2,4,6)
    unsigned ho = ((q & 0x08080808u) << 4) | mo;   // hi-bytes, odd  codes (k+1,3,5,7)
    unsigned bu0 = __builtin_amdgcn_perm(ho, he, 0x040C000Cu); // [0,he0,0,ho0]
    unsigned bu1 = __builtin_amdgcn_perm(ho, he, 0x050C010Cu);
    unsigned bu2 = __builtin_amdgcn_perm(ho, he, 0x060C020Cu);
    unsigned bu3 = __builtin_amdgcn_perm(ho, he, 0x070C030Cu);
    f16x2 sv = __builtin_bit_cast(f16x2, s2);
    f16x2 h0 = __builtin_bit_cast(f16x2, bu0) * sv;
    f16x2 h1 = __builtin_bit_cast(f16x2, bu1) * sv;
    f16x2 h2 = __builtin_bit_cast(f16x2, bu2) * sv;
    f16x2 h3 = __builtin_bit_cast(f16x2, bu3) * sv;
    f16x8 b;
    b[0]=h0[0]; b[1]=h0[1]; b[2]=h1[0]; b[3]=h1[1];
    b[4]=h2[0]; b[5]=h2[1]; b[6]=h3[0]; b[7]=h3[1];
    return b;
}

// Detect packed_weight upload format (int32-per-byte vs raw u8); zero t.
__global__ void detect_kernel(const unsigned* __restrict__ Wp,
                              int* __restrict__ flag, float* __restrict__ t) {
    unsigned v = Wp[threadIdx.x & 63];
    unsigned long long m = __ballot(v > 255u);
    if (threadIdx.x == 0) *flag = (m == 0ull) ? 1 : 0;
    for (int i = threadIdx.x; i < MB * RANK; i += 256) t[i] = 0.f;
}

// prep: grid (64 m, 4 kq). Converts x quarter to MFMA-A-fragment layout and
// accumulates partial t = x.A^T via atomics (t zeroed by detect).
__global__ __launch_bounds__(256) void prep_kernel(
    const float* __restrict__ x, const float* __restrict__ lora_A,
    uint2* __restrict__ xf2, float* __restrict__ t)
{
    const int m = blockIdx.x, kq = blockIdx.y;
    const int tid = threadIdx.x;
    const int mt = m >> 4, l15 = m & 15;
    float acc[RANK];
#pragma unroll
    for (int r = 0; r < RANK; ++r) acc[r] = 0.f;

    const float4* x4 = (const float4*)(x + (size_t)m * IN_F);
    const float4* A4 = (const float4*)lora_A;
#pragma unroll
    for (int it = 0; it < 2; ++it) {
        int j = kq * 512 + it * 256 + tid;       // float4 index into the row
        float4 xv = x4[j];
        uint2 u;
        u.x = pk2h(xv.x, xv.y);
        u.y = pk2h(xv.z, xv.w);
        int kstep = j >> 3, quad = (j >> 1) & 3, h = j & 1;
        xf2[(size_t)(((kstep * 4 + mt) * 64 + quad * 16 + l15) * 2 + h)] = u;
#pragma unroll
        for (int r = 0; r < RANK; ++r) {
            float4 av = A4[(size_t)r * (IN_F / 4) + j];
            acc[r] += xv.x * av.x + xv.y * av.y + xv.z * av.z + xv.w * av.w;
        }
    }
#pragma unroll
    for (int r = 0; r < RANK; ++r)
#pragma unroll
        for (int off = 32; off > 0; off >>= 1)
            acc[r] += __shfl_down(acc[r], off);

    __shared__ float red[4][RANK];
    int lane = tid & 63, wid = tid >> 6;
    if (lane == 0) {
#pragma unroll
        for (int r = 0; r < RANK; ++r) red[wid][r] = acc[r];
    }
    __syncthreads();
    if (tid < RANK)
        atomicAdd(&t[m * RANK + tid],
                  red[0][tid] + red[1][tid] + red[2][tid] + red[3][tid]);
}

// lora: out = t @ B^T (SCALING=1). One float4 of out per thread.
__global__ __launch_bounds__(256) void lora_kernel(
    const float* __restrict__ t, const float* __restrict__ lora_B,
    float* __restrict__ out)
{
    const int gid = blockIdx.x * 256 + threadIdx.x;  // 0..131071 float4s
    const int m = gid >> 11;
    const int n4 = (gid & 2047) * 4;
    const float4* t4 = (const float4*)(t + m * RANK);
    float4 ta = t4[0], tb = t4[1], tc = t4[2], td = t4[3];
    float4 o;
    float* op = (float*)&o;
#pragma unroll
    for (int j = 0; j < 4; ++j) {
        const float4* B4 = (const float4*)(lora_B + (size_t)(n4 + j) * RANK);
        float4 b0 = B4[0], b1 = B4[1], b2 = B4[2], b3 = B4[3];
        op[j] = ta.x * b0.x + ta.y * b0.y + ta.z * b0.z + ta.w * b0.w
              + tb.x * b1.x + tb.y * b1.y + tb.z * b1.z + tb.w * b1.w
              + tc.x * b2.x + tc.y * b2.y + tc.z * b2.z + tc.w * b2.w
              + td.x * b3.x + td.y * b3.y + td.z * b3.z + td.w * b3.w;
    }
    ((float4*)out)[gid] = o;
}

// main: block = 1024 thr (16 waves) owns 16 n-columns; wave w handles
// k-slice [w*512, w*512+512). LDS reduce across waves, then out += sum.
// No atomics, no k-split across blocks. grid = OUT_F/16 = 512.
template<int FMT>
__global__ __launch_bounds__(1024, 4) void main_kernel(
    const void*  __restrict__ Wpv,
    const float* __restrict__ scales,
    const uint4* __restrict__ xf4,
    const int*   __restrict__ flag,
    float*       __restrict__ out)
{
    if (*flag != FMT) return;

    __shared__ float lds[16 * 1024];   // 64 KiB: per-wave 64m x 16n partials

    const int tid = threadIdx.x;
    const int lane = tid & 63, w = tid >> 6;      // w = k-slice
    const int l15 = lane & 15, quad = lane >> 4;
    const int n0 = blockIdx.x * 16;
    const int row = n0 + l15;

    f32x4 acc[4];
#pragma unroll
    for (int mt = 0; mt < 4; ++mt) acc[mt] = (f32x4){0.f, 0.f, 0.f, 0.f};

    const uint4*    wi = (const uint4*)Wpv + (size_t)row * (IN_F / 8) + w * 64 + quad;
    const unsigned* wb = (const unsigned*)((const uint8_t*)Wpv
                         + (size_t)row * (IN_F / 2)) + w * 64 + quad;
    const float*    sp = scales + (size_t)row * (IN_F / 16) + w * 32 + (quad >> 1);

#pragma unroll 4
    for (int s = 0; s < 16; ++s) {                // 16 k-steps of 32
        const int kstep = w * 16 + s;
        f16x8 afr[4];
#pragma unroll
        for (int mt = 0; mt < 4; ++mt)
            afr[mt] = __builtin_bit_cast(f16x8, xf4[(size_t)(kstep * 4 + mt) * 64 + lane]);

        unsigned p;
        if (FMT == 1) {
            uint4 v = wi[s * 4];                  // 4 int32, one code-byte each
            p = v.x | (v.y << 8) | (v.z << 16) | (v.w << 24);
        } else {
            p = wb[s * 4];                        // 4 raw packed bytes
        }
        float sc = sp[s * 2];
        unsigned s2 = pk2h(sc, sc);
        f16x8 b = decode8(p, s2);
#pragma unroll
        for (int mt = 0; mt < 4; ++mt)
            acc[mt] = __builtin_amdgcn_mfma_f32_16x16x32_f16(afr[mt], b, acc[mt], 0, 0, 0);
    }

    // LDS: wave-w tile at lds[w*1024 + m*16 + nl]; C/D: m=quad*4+r+16*mt, n=l15
#pragma unroll
    for (int mt = 0; mt < 4; ++mt)
#pragma unroll
        for (int r = 0; r < 4; ++r)
            lds[w * 1024 + (mt * 16 + quad * 4 + r) * 16 + l15] = acc[mt][r];
    __syncthreads();

    float sum = 0.f;
#pragma unroll
    for (int w2 = 0; w2 < 16; ++w2) sum += lds[w2 * 1024 + tid];
    const int m = tid >> 4, nl = tid & 15;
    const size_t idx = (size_t)m * OUT_F + n0 + nl;
    out[idx] += sum;                              // lora term pre-written
}

extern "C" void kernel_launch(void* const* d_in, const int* in_sizes, int n_in,
                              void* d_out, int out_size, void* d_ws, size_t ws_size,
                              hipStream_t stream)
{
    (void)in_sizes; (void)n_in; (void)out_size; (void)ws_size;
    const float* x      = (const float*)d_in[0];
    const void*  Wp     = (const void*)d_in[1];
    const float* scales = (const float*)d_in[2];
    const float* lora_A = (const float*)d_in[3];
    const float* lora_B = (const float*)d_in[4];
    float* out = (float*)d_out;

    char* ws = (char*)d_ws;
    int*   flag = (int*)ws;                  // 4 B
    float* t    = (float*)(ws + 4096);       // 4 KiB
    uint2* xf   = (uint2*)(ws + 65536);      // 1 MiB fragment-layout fp16 x

    detect_kernel<<<1, 256, 0, stream>>>((const unsigned*)Wp, flag, t);
    prep_kernel<<<dim3(64, 4), 256, 0, stream>>>(x, lora_A, xf, t);
    lora_kernel<<<512, 256, 0, stream>>>(t, lora_B, out);
    main_kernel<1><<<OUT_F / 16, 1024, 0, stream>>>(
        Wp, scales, (const uint4*)xf, flag, out);
    main_kernel<0><<<OUT_F / 16, 1024, 0, stream>>>(
        Wp, scales, (const uint4*)xf, flag, out);
}

// Round 7
// 252.455 us; speedup vs baseline: 1.3036x; 1.0236x over previous
//
#include <hip/hip_runtime.h>
#include <stdint.h>

#define IN_F   8192
#define OUT_F  8192
#define MB     64
#define RANK   16

typedef _Float16 f16x8 __attribute__((ext_vector_type(8)));
typedef _Float16 f16x2 __attribute__((ext_vector_type(2)));
typedef float    f32x4 __attribute__((ext_vector_type(4)));

__device__ __forceinline__ unsigned pk2h(float a, float b) {
    return __builtin_bit_cast(unsigned, __builtin_amdgcn_cvt_pkrtz(a, b));
}

// Decode 8 nvfp4 codes (packed dword p, byte i = codes 2i,2i+1) into f16x8
// scaled by s2 (f16x2 of block scale). v_perm LUT on f16 hi-bytes; sign via
// bit3<<4. Verified R5/R6 (absmax identical to scalar-LUT path).
__device__ __forceinline__ f16x8 decode8(unsigned p, unsigned s2) {
    unsigned q  = p >> 4;
    unsigned me = __builtin_amdgcn_perm(0x46444240u, 0x3E3C3800u, p & 0x07070707u);
    unsigned mo = __builtin_amdgcn_perm(0x46444240u, 0x3E3C3800u, q & 0x07070707u);
    unsigned he = ((p & 0x08080808u) << 4) | me;
    unsigned ho = ((q & 0x08080808u) << 4) | mo;
    unsigned bu0 = __builtin_amdgcn_perm(ho, he, 0x040C000Cu);
    unsigned bu1 = __builtin_amdgcn_perm(ho, he, 0x050C010Cu);
    unsigned bu2 = __builtin_amdgcn_perm(ho, he, 0x060C020Cu);
    unsigned bu3 = __builtin_amdgcn_perm(ho, he, 0x070C030Cu);
    f16x2 sv = __builtin_bit_cast(f16x2, s2);
    f16x2 h0 = __builtin_bit_cast(f16x2, bu0) * sv;
    f16x2 h1 = __builtin_bit_cast(f16x2, bu1) * sv;
    f16x2 h2 = __builtin_bit_cast(f16x2, bu2) * sv;
    f16x2 h3 = __builtin_bit_cast(f16x2, bu3) * sv;
    f16x8 b;
    b[0]=h0[0]; b[1]=h0[1]; b[2]=h1[0]; b[3]=h1[1];
    b[4]=h2[0]; b[5]=h2[1]; b[6]=h3[0]; b[7]=h3[1];
    return b;
}

// Detect packed_weight upload format (int32-per-byte vs raw u8); zero t.
__global__ void detect_kernel(const unsigned* __restrict__ Wp,
                              int* __restrict__ flag, float* __restrict__ t) {
    unsigned v = Wp[threadIdx.x & 63];
    unsigned long long m = __ballot(v > 255u);
    if (threadIdx.x == 0) *flag = (m == 0ull) ? 1 : 0;
    for (int i = threadIdx.x; i < MB * RANK; i += 256) t[i] = 0.f;
}

// prep: grid (64 m, 4 kq). x quarter -> MFMA-A-fragment layout; partial t.
__global__ __launch_bounds__(256) void prep_kernel(
    const float* __restrict__ x, const float* __restrict__ lora_A,
    uint2* __restrict__ xf2, float* __restrict__ t)
{
    const int m = blockIdx.x, kq = blockIdx.y;
    const int tid = threadIdx.x;
    const int mt = m >> 4, l15 = m & 15;
    float acc[RANK];
#pragma unroll
    for (int r = 0; r < RANK; ++r) acc[r] = 0.f;

    const float4* x4 = (const float4*)(x + (size_t)m * IN_F);
    const float4* A4 = (const float4*)lora_A;
#pragma unroll
    for (int it = 0; it < 2; ++it) {
        int j = kq * 512 + it * 256 + tid;
        float4 xv = x4[j];
        uint2 u;
        u.x = pk2h(xv.x, xv.y);
        u.y = pk2h(xv.z, xv.w);
        int kstep = j >> 3, quad = (j >> 1) & 3, h = j & 1;
        xf2[(size_t)(((kstep * 4 + mt) * 64 + quad * 16 + l15) * 2 + h)] = u;
#pragma unroll
        for (int r = 0; r < RANK; ++r) {
            float4 av = A4[(size_t)r * (IN_F / 4) + j];
            acc[r] += xv.x * av.x + xv.y * av.y + xv.z * av.z + xv.w * av.w;
        }
    }
#pragma unroll
    for (int r = 0; r < RANK; ++r)
#pragma unroll
        for (int off = 32; off > 0; off >>= 1)
            acc[r] += __shfl_down(acc[r], off);

    __shared__ float red[4][RANK];
    int lane = tid & 63, wid = tid >> 6;
    if (lane == 0) {
#pragma unroll
        for (int r = 0; r < RANK; ++r) red[wid][r] = acc[r];
    }
    __syncthreads();
    if (tid < RANK)
        atomicAdd(&t[m * RANK + tid],
                  red[0][tid] + red[1][tid] + red[2][tid] + red[3][tid]);
}

// lora: out = t @ B^T. One float4 of out per thread.
__global__ __launch_bounds__(256) void lora_kernel(
    const float* __restrict__ t, const float* __restrict__ lora_B,
    float* __restrict__ out)
{
    const int gid = blockIdx.x * 256 + threadIdx.x;
    const int m = gid >> 11;
    const int n4 = (gid & 2047) * 4;
    const float4* t4 = (const float4*)(t + m * RANK);
    float4 ta = t4[0], tb = t4[1], tc = t4[2], td = t4[3];
    float4 o;
    float* op = (float*)&o;
#pragma unroll
    for (int j = 0; j < 4; ++j) {
        const float4* B4 = (const float4*)(lora_B + (size_t)(n4 + j) * RANK);
        float4 b0 = B4[0], b1 = B4[1], b2 = B4[2], b3 = B4[3];
        op[j] = ta.x * b0.x + ta.y * b0.y + ta.z * b0.z + ta.w * b0.w
              + tb.x * b1.x + tb.y * b1.y + tb.z * b1.z + tb.w * b1.w
              + tc.x * b2.x + tc.y * b2.y + tc.z * b2.z + tc.w * b2.w
              + td.x * b3.x + td.y * b3.y + td.z * b3.z + td.w * b3.w;
    }
    ((float4*)out)[gid] = o;
}

// main: grid 512 (16 n each), block 512 = 8 waves; wave w = k-slice of 1024
// (32 steps of 32 k). Software-pipelined: W+scale prefetched one 4-step chunk
// ahead, xf one step ahead. LDS cross-wave reduce, coalesced out +=.
template<int FMT>
__global__ __launch_bounds__(512, 4) void main_kernel(
    const void*  __restrict__ Wpv,
    const float* __restrict__ scales,
    const uint4* __restrict__ xf4,
    const int*   __restrict__ flag,
    float*       __restrict__ out)
{
    if (*flag != FMT) return;

    __shared__ float lds[8 * 1024];   // 32 KiB

    const int tid = threadIdx.x;
    const int lane = tid & 63, w = tid >> 6;        // w = k-slice 0..7
    const int l15 = lane & 15, quad = lane >> 4, qh = quad >> 1;
    const int n0 = blockIdx.x * 16;
    const int row = n0 + l15;

    f32x4 acc[4];
#pragma unroll
    for (int mt = 0; mt < 4; ++mt) acc[mt] = (f32x4){0.f, 0.f, 0.f, 0.f};

    // W: k/8 dword- or uint4-index; row stride IN_F/8 (=1024) in both views.
    const uint4*    wi  = (const uint4*)Wpv + (size_t)row * (IN_F / 8) + w * 128 + quad;
    const unsigned* wb  = (const unsigned*)Wpv + (size_t)row * (IN_F / 8) + w * 128 + quad;
    const float4*   sp4 = (const float4*)(scales + (size_t)row * (IN_F / 16)) + w * 16;
    const uint4*    xfp = xf4 + (size_t)(w * 32 * 4) * 64 + lane;

    // ping-pong buffers (all indices compile-time after full unroll)
    uint4 wvA[4], wvB[4];        // FMT=1: 4 steps x uint4
    unsigned wpA[4], wpB[4];     // FMT=0: 4 steps x dword
    float4 scA[2], scB[2];       // 8 scale floats per 4-step chunk
    uint4 xvA[4], xvB[4];        // one step of A-fragments (4 m-tiles)

#define LOADW(c, wv, wp, sc)                                             \
    do {                                                                 \
        if (FMT == 1) {                                                  \
            wv[0] = wi[(c)*16];     wv[1] = wi[(c)*16 + 4];              \
            wv[2] = wi[(c)*16 + 8]; wv[3] = wi[(c)*16 + 12];             \
        } else {                                                         \
            wp[0] = wb[(c)*16];     wp[1] = wb[(c)*16 + 4];              \
            wp[2] = wb[(c)*16 + 8]; wp[3] = wb[(c)*16 + 12];             \
        }                                                                \
        sc[0] = sp4[(c)*2]; sc[1] = sp4[(c)*2 + 1];                      \
    } while (0)

#define LOADX(s, xv)                                                     \
    do {                                                                 \
        xv[0] = xfp[(size_t)((s)*4 + 0) * 64];                           \
        xv[1] = xfp[(size_t)((s)*4 + 1) * 64];                           \
        xv[2] = xfp[(size_t)((s)*4 + 2) * 64];                           \
        xv[3] = xfp[(size_t)((s)*4 + 3) * 64];                           \
    } while (0)

#define STEPC(wv, wp, st, scf4, xv)                                      \
    do {                                                                 \
        unsigned p;                                                      \
        if (FMT == 1) {                                                  \
            uint4 v = wv[st];                                            \
            p = v.x | (v.y << 8) | (v.z << 16) | (v.w << 24);            \
        } else p = wp[st];                                               \
        float scf = ((st) & 1) ? (qh ? scf4[(st) >> 1].w : scf4[(st) >> 1].z) \
                               : (qh ? scf4[(st) >> 1].y : scf4[(st) >> 1].x); \
        unsigned s2 = pk2h(scf, scf);                                    \
        f16x8 b = decode8(p, s2);                                        \
        acc[0] = __builtin_amdgcn_mfma_f32_16x16x32_f16(                 \
            __builtin_bit_cast(f16x8, xv[0]), b, acc[0], 0, 0, 0);       \
        acc[1] = __builtin_amdgcn_mfma_f32_16x16x32_f16(                 \
            __builtin_bit_cast(f16x8, xv[1]), b, acc[1], 0, 0, 0);       \
        acc[2] = __builtin_amdgcn_mfma_f32_16x16x32_f16(                 \
            __builtin_bit_cast(f16x8, xv[2]), b, acc[2], 0, 0, 0);       \
        acc[3] = __builtin_amdgcn_mfma_f32_16x16x32_f16(                 \
            __builtin_bit_cast(f16x8, xv[3]), b, acc[3], 0, 0, 0);       \
    } while (0)

    LOADW(0, wvA, wpA, scA);
    LOADX(0, xvA);

#pragma unroll
    for (int c = 0; c < 8; ++c) {
        const int s0 = c * 4;
        if ((c & 1) == 0) {
            if (c < 7) LOADW(c + 1, wvB, wpB, scB);
            LOADX(s0 + 1, xvB);  STEPC(wvA, wpA, 0, scA, xvA);
            LOADX(s0 + 2, xvA);  STEPC(wvA, wpA, 1, scA, xvB);
            LOADX(s0 + 3, xvB);  STEPC(wvA, wpA, 2, scA, xvA);
            if (s0 + 4 < 32) LOADX(s0 + 4, xvA);
            STEPC(wvA, wpA, 3, scA, xvB);
        } else {
            if (c < 7) LOADW(c + 1, wvA, wpA, scA);
            LOADX(s0 + 1, xvB);  STEPC(wvB, wpB, 0, scB, xvA);
            LOADX(s0 + 2, xvA);  STEPC(wvB, wpB, 1, scB, xvB);
            LOADX(s0 + 3, xvB);  STEPC(wvB, wpB, 2, scB, xvA);
            if (s0 + 4 < 32) LOADX(s0 + 4, xvA);
            STEPC(wvB, wpB, 3, scB, xvB);
        }
    }
#undef LOADW
#undef LOADX
#undef STEPC

    // LDS reduce: wave tile at lds[w*1024 + m*16 + nl]; C/D m=mt*16+quad*4+r, n=l15
#pragma unroll
    for (int mt = 0; mt < 4; ++mt)
#pragma unroll
        for (int r = 0; r < 4; ++r)
            lds[w * 1024 + (mt * 16 + quad * 4 + r) * 16 + l15] = acc[mt][r];
    __syncthreads();

    float s0 = 0.f, s1 = 0.f;
#pragma unroll
    for (int w2 = 0; w2 < 8; ++w2) {
        s0 += lds[w2 * 1024 + tid];
        s1 += lds[w2 * 1024 + 512 + tid];
    }
    const int m0 = tid >> 4, nl = tid & 15;
    out[(size_t)m0 * OUT_F + n0 + nl] += s0;          // lora pre-written
    out[(size_t)(m0 + 32) * OUT_F + n0 + nl] += s1;
}

extern "C" void kernel_launch(void* const* d_in, const int* in_sizes, int n_in,
                              void* d_out, int out_size, void* d_ws, size_t ws_size,
                              hipStream_t stream)
{
    (void)in_sizes; (void)n_in; (void)out_size; (void)ws_size;
    const float* x      = (const float*)d_in[0];
    const void*  Wp     = (const void*)d_in[1];
    const float* scales = (const float*)d_in[2];
    const float* lora_A = (const float*)d_in[3];
    const float* lora_B = (const float*)d_in[4];
    float* out = (float*)d_out;

    char* ws = (char*)d_ws;
    int*   flag = (int*)ws;                  // 4 B
    float* t    = (float*)(ws + 4096);       // 4 KiB
    uint2* xf   = (uint2*)(ws + 65536);      // 1 MiB fragment-layout fp16 x

    detect_kernel<<<1, 256, 0, stream>>>((const unsigned*)Wp, flag, t);
    prep_kernel<<<dim3(64, 4), 256, 0, stream>>>(x, lora_A, xf, t);
    lora_kernel<<<512, 256, 0, stream>>>(t, lora_B, out);
    main_kernel<1><<<OUT_F / 16, 512, 0, stream>>>(
        Wp, scales, (const uint4*)xf, flag, out);
    main_kernel<0><<<OUT_F / 16, 512, 0, stream>>>(
        Wp, scales, (const uint4*)xf, flag, out);
}

// Round 8
// 246.615 us; speedup vs baseline: 1.3345x; 1.0237x over previous
//
#include <hip/hip_runtime.h>
#include <stdint.h>

#define IN_F   8192
#define OUT_F  8192
#define MB     64
#define RANK   16
#define KSPLIT 16
#define KSTEPS 16   // ksteps (of 32 k) per block: 512 k per block

typedef _Float16 f16x8 __attribute__((ext_vector_type(8)));
typedef _Float16 f16x2 __attribute__((ext_vector_type(2)));
typedef float    f32x4 __attribute__((ext_vector_type(4)));

__device__ __forceinline__ unsigned pk2h(float a, float b) {
    return __builtin_bit_cast(unsigned, __builtin_amdgcn_cvt_pkrtz(a, b));
}

// Decode 8 nvfp4 codes (dword p, byte i = codes 2i,2i+1) -> f16x8 scaled by
// s2 (f16x2 block scale). v_perm hi-byte LUT + sign bit3<<4. Verified R5-R7.
__device__ __forceinline__ f16x8 decode8(unsigned p, unsigned s2) {
    unsigned q  = p >> 4;
    unsigned me = __builtin_amdgcn_perm(0x46444240u, 0x3E3C3800u, p & 0x07070707u);
    unsigned mo = __builtin_amdgcn_perm(0x46444240u, 0x3E3C3800u, q & 0x07070707u);
    unsigned he = ((p & 0x08080808u) << 4) | me;
    unsigned ho = ((q & 0x08080808u) << 4) | mo;
    unsigned bu0 = __builtin_amdgcn_perm(ho, he, 0x040C000Cu);
    unsigned bu1 = __builtin_amdgcn_perm(ho, he, 0x050C010Cu);
    unsigned bu2 = __builtin_amdgcn_perm(ho, he, 0x060C020Cu);
    unsigned bu3 = __builtin_amdgcn_perm(ho, he, 0x070C030Cu);
    f16x2 sv = __builtin_bit_cast(f16x2, s2);
    f16x2 h0 = __builtin_bit_cast(f16x2, bu0) * sv;
    f16x2 h1 = __builtin_bit_cast(f16x2, bu1) * sv;
    f16x2 h2 = __builtin_bit_cast(f16x2, bu2) * sv;
    f16x2 h3 = __builtin_bit_cast(f16x2, bu3) * sv;
    f16x8 b;
    b[0]=h0[0]; b[1]=h0[1]; b[2]=h1[0]; b[3]=h1[1];
    b[4]=h2[0]; b[5]=h2[1]; b[6]=h3[0]; b[7]=h3[1];
    return b;
}

// Detect packed_weight upload format (int32-per-byte vs raw u8); zero t.
__global__ void detect_kernel(const unsigned* __restrict__ Wp,
                              int* __restrict__ flag, float* __restrict__ t) {
    unsigned v = Wp[threadIdx.x & 63];
    unsigned long long m = __ballot(v > 255u);
    if (threadIdx.x == 0) *flag = (m == 0ull) ? 1 : 0;
    for (int i = threadIdx.x; i < MB * RANK; i += 256) t[i] = 0.f;
}

// prep: grid (64 m, 4 kq). x quarter -> MFMA-A-fragment layout; partial t.
__global__ __launch_bounds__(256) void prep_kernel(
    const float* __restrict__ x, const float* __restrict__ lora_A,
    uint2* __restrict__ xf2, float* __restrict__ t)
{
    const int m = blockIdx.x, kq = blockIdx.y;
    const int tid = threadIdx.x;
    const int mt = m >> 4, l15 = m & 15;
    float acc[RANK];
#pragma unroll
    for (int r = 0; r < RANK; ++r) acc[r] = 0.f;

    const float4* x4 = (const float4*)(x + (size_t)m * IN_F);
    const float4* A4 = (const float4*)lora_A;
#pragma unroll
    for (int it = 0; it < 2; ++it) {
        int j = kq * 512 + it * 256 + tid;
        float4 xv = x4[j];
        uint2 u;
        u.x = pk2h(xv.x, xv.y);
        u.y = pk2h(xv.z, xv.w);
        int kstep = j >> 3, quad = (j >> 1) & 3, h = j & 1;
        xf2[(size_t)(((kstep * 4 + mt) * 64 + quad * 16 + l15) * 2 + h)] = u;
#pragma unroll
        for (int r = 0; r < RANK; ++r) {
            float4 av = A4[(size_t)r * (IN_F / 4) + j];
            acc[r] += xv.x * av.x + xv.y * av.y + xv.z * av.z + xv.w * av.w;
        }
    }
#pragma unroll
    for (int r = 0; r < RANK; ++r)
#pragma unroll
        for (int off = 32; off > 0; off >>= 1)
            acc[r] += __shfl_down(acc[r], off);

    __shared__ float red[4][RANK];
    int lane = tid & 63, wid = tid >> 6;
    if (lane == 0) {
#pragma unroll
        for (int r = 0; r < RANK; ++r) red[wid][r] = acc[r];
    }
    __syncthreads();
    if (tid < RANK)
        atomicAdd(&t[m * RANK + tid],
                  red[0][tid] + red[1][tid] + red[2][tid] + red[3][tid]);
}

// lora-only epilogue helper (dot of t-row with 4 B-rows)
__device__ __forceinline__ float4 lora4(const float* __restrict__ t, int m,
                                        const float* __restrict__ lora_B, int n4) {
    const float4* t4 = (const float4*)(t + m * RANK);
    float4 ta = t4[0], tb = t4[1], tc = t4[2], td = t4[3];
    float4 o;
    float* op = (float*)&o;
#pragma unroll
    for (int j = 0; j < 4; ++j) {
        const float4* B4 = (const float4*)(lora_B + (size_t)(n4 + j) * RANK);
        float4 b0 = B4[0], b1 = B4[1], b2 = B4[2], b3 = B4[3];
        op[j] = ta.x * b0.x + ta.y * b0.y + ta.z * b0.z + ta.w * b0.w
              + tb.x * b1.x + tb.y * b1.y + tb.z * b1.z + tb.w * b1.w
              + tc.x * b2.x + tc.y * b2.y + tc.z * b2.z + tc.w * b2.w
              + td.x * b3.x + td.y * b3.y + td.z * b3.z + td.w * b3.w;
    }
    return o;
}

// lora: out = t @ B^T (fallback path pre-write)
__global__ __launch_bounds__(256) void lora_kernel(
    const float* __restrict__ t, const float* __restrict__ lora_B,
    float* __restrict__ out)
{
    const int gid = blockIdx.x * 256 + threadIdx.x;
    ((float4*)out)[gid] = lora4(t, gid >> 11, lora_B, (gid & 2047) * 4);
}

// finish: out = sum_ks partial + t @ B^T
__global__ __launch_bounds__(256) void finish_kernel(
    const float* __restrict__ partial, const float* __restrict__ t,
    const float* __restrict__ lora_B, float* __restrict__ out)
{
    const int gid = blockIdx.x * 256 + threadIdx.x;   // float4 index
    float4 p = {0.f, 0.f, 0.f, 0.f};
#pragma unroll
    for (int ksp = 0; ksp < KSPLIT; ++ksp) {
        float4 v = ((const float4*)partial)[(size_t)ksp * (MB * OUT_F / 4) + gid];
        p.x += v.x; p.y += v.y; p.z += v.z; p.w += v.w;
    }
    float4 l = lora4(t, gid >> 11, lora_B, (gid & 2047) * 4);
    p.x += l.x; p.y += l.y; p.z += l.z; p.w += l.w;
    ((float4*)out)[gid] = p;
}

// main: grid (KSPLIT, 32), block 512 = 8 waves, wave owns 32 n x 64 m x 512 k.
// Whole xf k-slice staged to LDS once (single barrier); K-loop reads A-frags
// via ds_read (lgkmcnt) while W+scales run a depth-2 register pipeline on a
// clean vmcnt FIFO. ATOMIC=0: write partial[ks]; ATOMIC=1: atomicAdd onto out.
template<int FMT, int ATOMIC>
__global__ __launch_bounds__(512, 4) void main_kernel(
    const void*  __restrict__ Wpv,
    const float* __restrict__ scales,
    const uint4* __restrict__ xf4,
    const int*   __restrict__ flag,
    float*       __restrict__ dst)
{
    if (*flag != FMT) return;

    __shared__ __align__(16) char xs[65536];   // 64 KiB: 16 ksteps x 4 mt x 64 lanes x 16B

    const int tid = threadIdx.x;
    const int lane = tid & 63, w = tid >> 6;
    const int l15 = lane & 15, quad = lane >> 4, qh = quad >> 1;
    const int ks = blockIdx.x;
    const int n0 = blockIdx.y * 256 + w * 32;
    const int row = n0 + l15;

    // ---- one-time stage of the block's xf slice into LDS ----
    {
        const uint4* gsrc = xf4 + (size_t)ks * (KSTEPS * 4 * 64);
#pragma unroll
        for (int i = 0; i < 8; ++i) {
            int idx = i * 512 + tid;
            uint4 v = gsrc[idx];
            *(uint4*)&xs[(size_t)idx * 16] = v;
        }
    }
    __syncthreads();

    f32x4 acc[4][2];
#pragma unroll
    for (int mt = 0; mt < 4; ++mt)
#pragma unroll
        for (int nt = 0; nt < 2; ++nt)
            acc[mt][nt] = (f32x4){0.f, 0.f, 0.f, 0.f};

    // W pointers: uint4 view (FMT=1, int32 codes) / dword view (FMT=0, raw u8)
    const uint4*    wi0 = (const uint4*)Wpv + (size_t)row * (IN_F / 8) + ks * 64 + quad;
    const uint4*    wi1 = wi0 + (size_t)16 * (IN_F / 8);
    const unsigned* wb0 = (const unsigned*)Wpv + (size_t)row * (IN_F / 8) + ks * 64 + quad;
    const unsigned* wb1 = wb0 + (size_t)16 * (IN_F / 8);
    const float4*   sp4 = (const float4*)(scales + (size_t)row * (IN_F / 16) + ks * 32);
    const float4*   sq4 = (const float4*)(scales + (size_t)(row + 16) * (IN_F / 16) + ks * 32);

    uint4    wv[2][2][4];   // [buf][nt][step-in-chunk]  (FMT=1)
    unsigned wp[2][2][4];   // (FMT=0)
    float4   sc[2][2][2];   // [buf][nt][half]: 8 scale floats per chunk per nt

#define LOADCH(buf, c)                                                   \
    do {                                                                 \
        _Pragma("unroll")                                                \
        for (int j = 0; j < 4; ++j) {                                    \
            if (FMT == 1) {                                              \
                wv[buf][0][j] = wi0[((c) * 4 + j) * 4];                  \
                wv[buf][1][j] = wi1[((c) * 4 + j) * 4];                  \
            } else {                                                     \
                wp[buf][0][j] = wb0[((c) * 4 + j) * 4];                  \
                wp[buf][1][j] = wb1[((c) * 4 + j) * 4];                  \
            }                                                            \
        }                                                                \
        sc[buf][0][0] = sp4[(c) * 2]; sc[buf][0][1] = sp4[(c) * 2 + 1];  \
        sc[buf][1][0] = sq4[(c) * 2]; sc[buf][1][1] = sq4[(c) * 2 + 1];  \
    } while (0)

    LOADCH(0, 0);
    LOADCH(1, 1);

#pragma unroll
    for (int c = 0; c < 4; ++c) {
        const int buf = c & 1;
#pragma unroll
        for (int j = 0; j < 4; ++j) {
            const int s = c * 4 + j;
            f16x8 afr[4];
#pragma unroll
            for (int mt = 0; mt < 4; ++mt)
                afr[mt] = *(const f16x8*)&xs[(size_t)(((s * 4 + mt) * 64) + lane) * 16];
#pragma unroll
            for (int nt = 0; nt < 2; ++nt) {
                float4 v = sc[buf][nt][j >> 1];
                float scf = (j & 1) ? (qh ? v.w : v.z) : (qh ? v.y : v.x);
                unsigned s2 = pk2h(scf, scf);
                unsigned p;
                if (FMT == 1) {
                    uint4 u = wv[buf][nt][j];
                    p = u.x | (u.y << 8) | (u.z << 16) | (u.w << 24);
                } else {
                    p = wp[buf][nt][j];
                }
                f16x8 b = decode8(p, s2);
#pragma unroll
                for (int mt = 0; mt < 4; ++mt)
                    acc[mt][nt] = __builtin_amdgcn_mfma_f32_16x16x32_f16(
                        afr[mt], b, acc[mt][nt], 0, 0, 0);
            }
        }
        if (c < 2) LOADCH(buf, c + 2);
    }
#undef LOADCH

    // epilogue: C/D layout col(n)=l15, row(m)=quad*4+r (+16*mt)
    if (ATOMIC == 0) {
        float* pb = dst + (size_t)ks * (MB * OUT_F);
#pragma unroll
        for (int mt = 0; mt < 4; ++mt)
#pragma unroll
            for (int nt = 0; nt < 2; ++nt)
#pragma unroll
                for (int r = 0; r < 4; ++r)
                    pb[(size_t)(mt * 16 + quad * 4 + r) * OUT_F + n0 + nt * 16 + l15]
                        = acc[mt][nt][r];
    } else {
#pragma unroll
        for (int mt = 0; mt < 4; ++mt)
#pragma unroll
            for (int nt = 0; nt < 2; ++nt)
#pragma unroll
                for (int r = 0; r < 4; ++r)
                    atomicAdd(&dst[(size_t)(mt * 16 + quad * 4 + r) * OUT_F
                                   + n0 + nt * 16 + l15], acc[mt][nt][r]);
    }
}

extern "C" void kernel_launch(void* const* d_in, const int* in_sizes, int n_in,
                              void* d_out, int out_size, void* d_ws, size_t ws_size,
                              hipStream_t stream)
{
    (void)in_sizes; (void)n_in; (void)out_size;
    const float* x      = (const float*)d_in[0];
    const void*  Wp     = (const void*)d_in[1];
    const float* scales = (const float*)d_in[2];
    const float* lora_A = (const float*)d_in[3];
    const float* lora_B = (const float*)d_in[4];
    float* out = (float*)d_out;

    char* ws = (char*)d_ws;
    int*   flag    = (int*)ws;                   // 4 B
    float* t       = (float*)(ws + 4096);        // 4 KiB
    uint2* xf      = (uint2*)(ws + 65536);       // 1 MiB fragment-layout fp16 x
    float* partial = (float*)(ws + (2u << 20));  // KSPLIT * 2 MiB = 32 MiB

    const bool big_ws = ws_size >= ((size_t)34 << 20);

    detect_kernel<<<1, 256, 0, stream>>>((const unsigned*)Wp, flag, t);
    prep_kernel<<<dim3(64, 4), 256, 0, stream>>>(x, lora_A, xf, t);

    if (big_ws) {
        main_kernel<1, 0><<<dim3(KSPLIT, 32), 512, 0, stream>>>(
            Wp, scales, (const uint4*)xf, flag, partial);
        main_kernel<0, 0><<<dim3(KSPLIT, 32), 512, 0, stream>>>(
            Wp, scales, (const uint4*)xf, flag, partial);
        finish_kernel<<<(MB * OUT_F / 4) / 256, 256, 0, stream>>>(
            partial, t, lora_B, out);
    } else {
        lora_kernel<<<(MB * OUT_F / 4) / 256, 256, 0, stream>>>(t, lora_B, out);
        main_kernel<1, 1><<<dim3(KSPLIT, 32), 512, 0, stream>>>(
            Wp, scales, (const uint4*)xf, flag, out);
        main_kernel<0, 1><<<dim3(KSPLIT, 32), 512, 0, stream>>>(
            Wp, scales, (const uint4*)xf, flag, out);
    }
}

// Round 9
// 241.207 us; speedup vs baseline: 1.3644x; 1.0224x over previous
//
#include <hip/hip_runtime.h>
#include <stdint.h>

#define IN_F   8192
#define OUT_F  8192
#define MB     64
#define RANK   16
#define KSPLIT 16
#define KSTEPS 16   // ksteps (of 32 k) per block

typedef _Float16 f16x8 __attribute__((ext_vector_type(8)));
typedef _Float16 f16x2 __attribute__((ext_vector_type(2)));
typedef float    f32x4 __attribute__((ext_vector_type(4)));

__device__ __forceinline__ unsigned pk2h(float a, float b) {
    return __builtin_bit_cast(unsigned, __builtin_amdgcn_cvt_pkrtz(a, b));
}

// async global->LDS, 16B/lane and 4B/lane. dest is wave-uniform base + lane*size.
__device__ __forceinline__ void glds16(const void* gp, void* lp) {
    __builtin_amdgcn_global_load_lds(
        (const __attribute__((address_space(1))) void*)gp,
        (__attribute__((address_space(3))) void*)lp, 16, 0, 0);
}
__device__ __forceinline__ void glds4(const void* gp, void* lp) {
    __builtin_amdgcn_global_load_lds(
        (const __attribute__((address_space(1))) void*)gp,
        (__attribute__((address_space(3))) void*)lp, 4, 0, 0);
}
#define MEMBAR() __asm__ __volatile__("" ::: "memory")

// Decode 8 nvfp4 codes (dword p) -> f16x8 scaled by s2 (packed f16 pair).
// v_perm hi-byte LUT + sign bit3<<4. Verified R5-R8.
__device__ __forceinline__ f16x8 decode8(unsigned p, unsigned s2) {
    unsigned q  = p >> 4;
    unsigned me = __builtin_amdgcn_perm(0x46444240u, 0x3E3C3800u, p & 0x07070707u);
    unsigned mo = __builtin_amdgcn_perm(0x46444240u, 0x3E3C3800u, q & 0x07070707u);
    unsigned he = ((p & 0x08080808u) << 4) | me;
    unsigned ho = ((q & 0x08080808u) << 4) | mo;
    unsigned bu0 = __builtin_amdgcn_perm(ho, he, 0x040C000Cu);
    unsigned bu1 = __builtin_amdgcn_perm(ho, he, 0x050C010Cu);
    unsigned bu2 = __builtin_amdgcn_perm(ho, he, 0x060C020Cu);
    unsigned bu3 = __builtin_amdgcn_perm(ho, he, 0x070C030Cu);
    f16x2 sv = __builtin_bit_cast(f16x2, s2);
    f16x2 h0 = __builtin_bit_cast(f16x2, bu0) * sv;
    f16x2 h1 = __builtin_bit_cast(f16x2, bu1) * sv;
    f16x2 h2 = __builtin_bit_cast(f16x2, bu2) * sv;
    f16x2 h3 = __builtin_bit_cast(f16x2, bu3) * sv;
    f16x8 b;
    b[0]=h0[0]; b[1]=h0[1]; b[2]=h1[0]; b[3]=h1[1];
    b[4]=h2[0]; b[5]=h2[1]; b[6]=h3[0]; b[7]=h3[1];
    return b;
}

__global__ void detect_kernel(const unsigned* __restrict__ Wp,
                              int* __restrict__ flag, float* __restrict__ t) {
    unsigned v = Wp[threadIdx.x & 63];
    unsigned long long m = __ballot(v > 255u);
    if (threadIdx.x == 0) *flag = (m == 0ull) ? 1 : 0;
    for (int i = threadIdx.x; i < MB * RANK; i += 256) t[i] = 0.f;
}

// prep: grid (64 m, 4 kq). x quarter -> MFMA-A-fragment layout; partial t.
__global__ __launch_bounds__(256) void prep_kernel(
    const float* __restrict__ x, const float* __restrict__ lora_A,
    uint2* __restrict__ xf2, float* __restrict__ t)
{
    const int m = blockIdx.x, kq = blockIdx.y;
    const int tid = threadIdx.x;
    const int mt = m >> 4, l15 = m & 15;
    float acc[RANK];
#pragma unroll
    for (int r = 0; r < RANK; ++r) acc[r] = 0.f;

    const float4* x4 = (const float4*)(x + (size_t)m * IN_F);
    const float4* A4 = (const float4*)lora_A;
#pragma unroll
    for (int it = 0; it < 2; ++it) {
        int j = kq * 512 + it * 256 + tid;
        float4 xv = x4[j];
        uint2 u;
        u.x = pk2h(xv.x, xv.y);
        u.y = pk2h(xv.z, xv.w);
        int kstep = j >> 3, quad = (j >> 1) & 3, h = j & 1;
        xf2[(size_t)(((kstep * 4 + mt) * 64 + quad * 16 + l15) * 2 + h)] = u;
#pragma unroll
        for (int r = 0; r < RANK; ++r) {
            float4 av = A4[(size_t)r * (IN_F / 4) + j];
            acc[r] += xv.x * av.x + xv.y * av.y + xv.z * av.z + xv.w * av.w;
        }
    }
#pragma unroll
    for (int r = 0; r < RANK; ++r)
#pragma unroll
        for (int off = 32; off > 0; off >>= 1)
            acc[r] += __shfl_down(acc[r], off);

    __shared__ float red[4][RANK];
    int lane = tid & 63, wid = tid >> 6;
    if (lane == 0) {
#pragma unroll
        for (int r = 0; r < RANK; ++r) red[wid][r] = acc[r];
    }
    __syncthreads();
    if (tid < RANK)
        atomicAdd(&t[m * RANK + tid],
                  red[0][tid] + red[1][tid] + red[2][tid] + red[3][tid]);
}

__device__ __forceinline__ float4 lora4(const float* __restrict__ t, int m,
                                        const float* __restrict__ lora_B, int n4) {
    const float4* t4 = (const float4*)(t + m * RANK);
    float4 ta = t4[0], tb = t4[1], tc = t4[2], td = t4[3];
    float4 o;
    float* op = (float*)&o;
#pragma unroll
    for (int j = 0; j < 4; ++j) {
        const float4* B4 = (const float4*)(lora_B + (size_t)(n4 + j) * RANK);
        float4 b0 = B4[0], b1 = B4[1], b2 = B4[2], b3 = B4[3];
        op[j] = ta.x * b0.x + ta.y * b0.y + ta.z * b0.z + ta.w * b0.w
              + tb.x * b1.x + tb.y * b1.y + tb.z * b1.z + tb.w * b1.w
              + tc.x * b2.x + tc.y * b2.y + tc.z * b2.z + tc.w * b2.w
              + td.x * b3.x + td.y * b3.y + td.z * b3.z + td.w * b3.w;
    }
    return o;
}

__global__ __launch_bounds__(256) void lora_kernel(
    const float* __restrict__ t, const float* __restrict__ lora_B,
    float* __restrict__ out)
{
    const int gid = blockIdx.x * 256 + threadIdx.x;
    ((float4*)out)[gid] = lora4(t, gid >> 11, lora_B, (gid & 2047) * 4);
}

__global__ __launch_bounds__(256) void finish_kernel(
    const float* __restrict__ partial, const float* __restrict__ t,
    const float* __restrict__ lora_B, float* __restrict__ out)
{
    const int gid = blockIdx.x * 256 + threadIdx.x;
    float4 p = {0.f, 0.f, 0.f, 0.f};
#pragma unroll
    for (int ksp = 0; ksp < KSPLIT; ++ksp) {
        float4 v = ((const float4*)partial)[(size_t)ksp * (MB * OUT_F / 4) + gid];
        p.x += v.x; p.y += v.y; p.z += v.z; p.w += v.w;
    }
    float4 l = lora4(t, gid >> 11, lora_B, (gid & 2047) * 4);
    p.x += l.x; p.y += l.y; p.z += l.z; p.w += l.w;
    ((float4*)out)[gid] = p;
}

// main: grid (KSPLIT, 32), block 512 = 8 waves; wave owns 32 n x 64 m x 512 k.
// xf slice staged to LDS once (single barrier). W streamed via async
// global_load_lds into a wave-private double buffer (chunk = 2 ksteps),
// gated by explicit s_waitcnt vmcnt(4). Scales pre-packed into 32 VGPRs.
template<int FMT, int ATOMIC>
__global__ __launch_bounds__(512, 4) void main_kernel(
    const void*  __restrict__ Wpv,
    const float* __restrict__ scales,
    const uint4* __restrict__ xf4,
    const int*   __restrict__ flag,
    float*       __restrict__ dst)
{
    if (*flag != FMT) return;

    __shared__ __align__(16) char xs[65536];   // xf: 16 ksteps x 4 mt x 64 lanes x 16B
    __shared__ __align__(16) char wl[65536];   // W:  8 waves x 2 buf x 4 slots x 1 KiB

    const int tid = threadIdx.x;
    const int lane = tid & 63, w = tid >> 6;
    const int l15 = lane & 15, quad = lane >> 4, qh = quad >> 1;
    const int ks = blockIdx.x;
    const int n0 = blockIdx.y * 256 + w * 32;
    const int row = n0 + l15;

    // ---- scale preload: 32 packed-f16 dwords (this lane's qh parity) ----
    unsigned sreg[2][KSTEPS];
    {
        const float4* sp0 = (const float4*)(scales + (size_t)row * (IN_F / 16) + ks * 32);
        const float4* sp1 = (const float4*)(scales + (size_t)(row + 16) * (IN_F / 16) + ks * 32);
#pragma unroll
        for (int nt = 0; nt < 2; ++nt) {
            const float4* sp = nt ? sp1 : sp0;
#pragma unroll
            for (int i = 0; i < 8; ++i) {
                float4 v = sp[i];
                float a = qh ? v.y : v.x, b = qh ? v.w : v.z;
                sreg[nt][2 * i]     = pk2h(a, a);
                sreg[nt][2 * i + 1] = pk2h(b, b);
            }
        }
    }

    // ---- one-time xf stage (barrier drains vmcnt -> clean FIFO after) ----
    {
        const uint4* gsrc = xf4 + (size_t)ks * (KSTEPS * 4 * 64);
#pragma unroll
        for (int i = 0; i < 8; ++i) {
            int idx = i * 512 + tid;
            uint4 v = gsrc[idx];
            *(uint4*)&xs[(size_t)idx * 16] = v;
        }
    }
    __syncthreads();

    f32x4 acc[4][2];
#pragma unroll
    for (int mt = 0; mt < 4; ++mt)
#pragma unroll
        for (int nt = 0; nt < 2; ++nt)
            acc[mt][nt] = (f32x4){0.f, 0.f, 0.f, 0.f};

    char* wlw = &wl[(size_t)w * 8192];   // wave-private 8 KiB (2 buf x 4 KiB)

    // issue one chunk (2 ksteps x 2 nt = 4 async loads) into buf
#define ISSUE(c, buf)                                                        \
    do {                                                                     \
        _Pragma("unroll") for (int j = 0; j < 2; ++j)                        \
        _Pragma("unroll") for (int nt = 0; nt < 2; ++nt) {                   \
            size_t e = (size_t)(row + nt * 16) * 1024                        \
                       + (ks * 64 + ((c) * 2 + j) * 4 + quad);               \
            char* ldst = &wlw[(size_t)((buf) * 4 + j * 2 + nt) * 1024];      \
            if (FMT == 1) glds16((const char*)Wpv + e * 16, ldst);           \
            else          glds4 ((const char*)Wpv + e * 4,  ldst);           \
        }                                                                    \
    } while (0)

    ISSUE(0, 0);
    ISSUE(1, 1);

#pragma unroll
    for (int c = 0; c < 8; ++c) {
        const int buf = c & 1;
        MEMBAR();
        if (c < 7) __builtin_amdgcn_s_waitcnt(0x0F74);   // vmcnt(4): chunk c landed
        else       __builtin_amdgcn_s_waitcnt(0x0F70);   // vmcnt(0): last chunk
        MEMBAR();
#pragma unroll
        for (int j = 0; j < 2; ++j) {
            const int s = c * 2 + j;
            f16x8 afr[4];
#pragma unroll
            for (int mt = 0; mt < 4; ++mt)
                afr[mt] = *(const f16x8*)&xs[(size_t)((s * 4 + mt) * 64 + lane) * 16];
#pragma unroll
            for (int nt = 0; nt < 2; ++nt) {
                const char* slot = &wlw[(size_t)(buf * 4 + j * 2 + nt) * 1024];
                unsigned p;
                if (FMT == 1) {
                    uint4 u = *(const uint4*)(slot + (size_t)lane * 16);
                    p = u.x | (u.y << 8) | (u.z << 16) | (u.w << 24);
                } else {
                    p = *(const unsigned*)(slot + (size_t)lane * 4);
                }
                f16x8 b = decode8(p, sreg[nt][s]);
#pragma unroll
                for (int mt = 0; mt < 4; ++mt)
                    acc[mt][nt] = __builtin_amdgcn_mfma_f32_16x16x32_f16(
                        afr[mt], b, acc[mt][nt], 0, 0, 0);
            }
        }
        if (c < 6) { MEMBAR(); ISSUE(c + 2, buf); }
    }
#undef ISSUE

    // epilogue: C/D col(n)=l15, row(m)=quad*4+r (+16*mt)
    if (ATOMIC == 0) {
        float* pb = dst + (size_t)ks * (MB * OUT_F);
#pragma unroll
        for (int mt = 0; mt < 4; ++mt)
#pragma unroll
            for (int nt = 0; nt < 2; ++nt)
#pragma unroll
                for (int r = 0; r < 4; ++r)
                    pb[(size_t)(mt * 16 + quad * 4 + r) * OUT_F + n0 + nt * 16 + l15]
                        = acc[mt][nt][r];
    } else {
#pragma unroll
        for (int mt = 0; mt < 4; ++mt)
#pragma unroll
            for (int nt = 0; nt < 2; ++nt)
#pragma unroll
                for (int r = 0; r < 4; ++r)
                    atomicAdd(&dst[(size_t)(mt * 16 + quad * 4 + r) * OUT_F
                                   + n0 + nt * 16 + l15], acc[mt][nt][r]);
    }
}

extern "C" void kernel_launch(void* const* d_in, const int* in_sizes, int n_in,
                              void* d_out, int out_size, void* d_ws, size_t ws_size,
                              hipStream_t stream)
{
    (void)in_sizes; (void)n_in; (void)out_size;
    const float* x      = (const float*)d_in[0];
    const void*  Wp     = (const void*)d_in[1];
    const float* scales = (const float*)d_in[2];
    const float* lora_A = (const float*)d_in[3];
    const float* lora_B = (const float*)d_in[4];
    float* out = (float*)d_out;

    char* ws = (char*)d_ws;
    int*   flag    = (int*)ws;                   // 4 B
    float* t       = (float*)(ws + 4096);        // 4 KiB
    uint2* xf      = (uint2*)(ws + 65536);       // 1 MiB fragment-layout fp16 x
    float* partial = (float*)(ws + (2u << 20));  // KSPLIT * 2 MiB = 32 MiB

    const bool big_ws = ws_size >= ((size_t)34 << 20);

    detect_kernel<<<1, 256, 0, stream>>>((const unsigned*)Wp, flag, t);
    prep_kernel<<<dim3(64, 4), 256, 0, stream>>>(x, lora_A, xf, t);

    if (big_ws) {
        main_kernel<1, 0><<<dim3(KSPLIT, 32), 512, 0, stream>>>(
            Wp, scales, (const uint4*)xf, flag, partial);
        main_kernel<0, 0><<<dim3(KSPLIT, 32), 512, 0, stream>>>(
            Wp, scales, (const uint4*)xf, flag, partial);
        finish_kernel<<<(MB * OUT_F / 4) / 256, 256, 0, stream>>>(
            partial, t, lora_B, out);
    } else {
        lora_kernel<<<(MB * OUT_F / 4) / 256, 256, 0, stream>>>(t, lora_B, out);
        main_kernel<1, 1><<<dim3(KSPLIT, 32), 512, 0, stream>>>(
            Wp, scales, (const uint4*)xf, flag, out);
        main_kernel<0, 1><<<dim3(KSPLIT, 32), 512, 0, stream>>>(
            Wp, scales, (const uint4*)xf, flag, out);
    }
}